// Round 9
// baseline (369.838 us; speedup 1.0000x reference)
//
#include <hip/hip_runtime.h>
#include <hip/hip_bf16.h>
#include <stdint.h>

// ---------------------------------------------------------------------------
// DecoderOnlyTransformer: x@Wq/Wk/Wv -> transposed-softmax attention -> @Wo
//   -> (l2norm dropped: exact cancellation) -> @Wff -> l2norm -> gelu(exact).
// B=2 S=2048 D=L=1024 H=16 dh=64.  Inputs fp32 (auto-detect fallback).
// Softmax over QUERY axis; |scores|<1 so max-subtraction dropped (exact).
// Q pre-scaled by 0.03125*log2(e); V rows pre-scaled by r_k.
// attn_pv2: S computed in D[k][q] layout whose C-regs ARE the B-operand of
// mfma 16x16x16 -> P never touches LDS.
// attn_stats (round 9): 128-q tiles (2x compute per barrier, covers L3
// staging latency), __launch_bounds__(256,4) to cap VGPR<=128 (was 160 ->
// 3 waves/SIMD, 60% stall), constant-stride staging pointers, bh-major grid.
// LESSON (round 7): never gate LAUNCH-site code on __has_builtin.
// ---------------------------------------------------------------------------

typedef __attribute__((ext_vector_type(8))) short short8;   // 8 x bf16
typedef __attribute__((ext_vector_type(4))) short short4v;  // 4 x bf16
typedef __attribute__((ext_vector_type(4))) float floatx4;

#define MFMA_BF16(a, b, c) __builtin_amdgcn_mfma_f32_16x16x32_bf16((a), (b), (c), 0, 0, 0)
#define MFMA16(a, b, c) __builtin_amdgcn_mfma_f32_16x16x16bf16_1k((a), (b), (c), 0, 0, 0)

#if defined(__HIP_DEVICE_COMPILE__)
#define EXP2F(x) __builtin_amdgcn_exp2f(x)
#else
#define EXP2F(x) exp2f(x)
#endif

__device__ __forceinline__ float bf2f(unsigned short u) {
  union { unsigned int i; float f; } v; v.i = ((unsigned int)u) << 16; return v.f;
}
__device__ __forceinline__ unsigned short f2bf(float f) {
  __hip_bfloat16 h = __float2bfloat16(f);
  return *reinterpret_cast<unsigned short*>(&h);
}
__device__ __forceinline__ void gld_lds16(const void* g, void* l) {
  __builtin_amdgcn_global_load_lds((__attribute__((address_space(1))) void*)g,
                                   (__attribute__((address_space(3))) void*)l,
                                   16, 0, 0);
}

// ---------------------------------------------------------------------------
__global__ __launch_bounds__(256) void detect_dtype(const unsigned int* __restrict__ x,
                                                    int* __restrict__ flag)
{
  __shared__ int red[4];
  int ok = 0;
  for (int i = 0; i < 16; ++i) {
    const unsigned int w = x[threadIdx.x * 16 + i];
    const unsigned int e = (w >> 7) & 0xFF;
    ok += (e == 0 || (e >= 96 && e <= 144)) ? 1 : 0;
  }
  for (int off = 32; off > 0; off >>= 1) ok += __shfl_down(ok, off, 64);
  if ((threadIdx.x & 63) == 0) red[threadIdx.x >> 6] = ok;
  __syncthreads();
  if (threadIdx.x == 0)
    *flag = ((red[0] + red[1] + red[2] + red[3]) > 2048) ? 1 : 0;
}

__global__ __launch_bounds__(256) void cvt_x(const void* __restrict__ src,
                                             unsigned short* __restrict__ dst,
                                             const int* __restrict__ flag)
{
  const int i = blockIdx.x * 256 + threadIdx.x;
  if (*flag) {
    ((uint4*)dst)[i] = ((const uint4*)src)[i];
  } else {
    const float4 a = ((const float4*)src)[2 * i];
    const float4 b = ((const float4*)src)[2 * i + 1];
    unsigned short o[8] = {f2bf(a.x), f2bf(a.y), f2bf(a.z), f2bf(a.w),
                           f2bf(b.x), f2bf(b.y), f2bf(b.z), f2bf(b.w)};
    ((uint4*)dst)[i] = *(uint4*)o;
  }
}

// ---------------------------------------------------------------------------
// C[M,N] = A[M,K] @ Bt[N,K]^T, tile 128x64, BK=32.
// ---------------------------------------------------------------------------
__global__ __launch_bounds__(256) void gemm_bt_128x64(
    const unsigned short* __restrict__ A, const unsigned short* __restrict__ Bt,
    unsigned short* __restrict__ C, int M, int N, int K, int lda, int ldb, int ldc,
    int qscale_cols)
{
  __shared__ __align__(16) unsigned short sA[128 * 32];
  __shared__ __align__(16) unsigned short sB[64 * 32];
  const int tid = threadIdx.x;
  const int wave = tid >> 6, lane = tid & 63, l15 = lane & 15, quad = lane >> 4;
  const int m0 = blockIdx.x * 128, n0 = blockIdx.y * 64;

  const floatx4 z4 = {0.f, 0.f, 0.f, 0.f};
  floatx4 acc[2][4];
  for (int i = 0; i < 2; ++i) for (int j = 0; j < 4; ++j) acc[i][j] = z4;

  const int NK = K >> 5;
  auto stage = [&](int kt) {
    const int k0 = kt << 5;
    for (int j = 0; j < 2; ++j) {
      const int ci = j * 256 + wave * 64 + lane;
      gld_lds16(A + (size_t)(m0 + (ci >> 2)) * lda + k0 + (ci & 3) * 8,
                &sA[(j * 256 + wave * 64) * 8]);
    }
    {
      const int ci = wave * 64 + lane;
      gld_lds16(Bt + (size_t)(n0 + (ci >> 2)) * ldb + k0 + (ci & 3) * 8,
                &sB[(wave * 64) * 8]);
    }
  };

  stage(0);
  for (int kt = 0; kt < NK; ++kt) {
    __syncthreads();
    short8 af[2], bf[4];
    for (int mt = 0; mt < 2; ++mt)
      af[mt] = *(const short8*)&sA[(wave * 32 + mt * 16 + l15) * 32 + quad * 8];
    for (int nt = 0; nt < 4; ++nt)
      bf[nt] = *(const short8*)&sB[(nt * 16 + l15) * 32 + quad * 8];
    for (int mt = 0; mt < 2; ++mt)
      for (int nt = 0; nt < 4; ++nt)
        acc[mt][nt] = MFMA_BF16(af[mt], bf[nt], acc[mt][nt]);
    __syncthreads();
    if (kt + 1 < NK) stage(kt + 1);
  }
  for (int mt = 0; mt < 2; ++mt)
    for (int nt = 0; nt < 4; ++nt)
      for (int r = 0; r < 4; ++r) {
        const int row = m0 + wave * 32 + mt * 16 + quad * 4 + r;
        const int col = n0 + nt * 16 + l15;
        float v = acc[mt][nt][r];
        if (col < qscale_cols) v *= 0.04508422f;
        C[(size_t)row * ldc + col] = f2bf(v);
      }
}

// ---------------------------------------------------------------------------
// C[M,N] = A[M,K] @ Bt[N,K]^T, tile 128x128 (m97 shape), BK=32, 2x2 waves.
// ---------------------------------------------------------------------------
__global__ __launch_bounds__(256) void gemm_bt_128x128(
    const unsigned short* __restrict__ A, const unsigned short* __restrict__ Bt,
    unsigned short* __restrict__ C, int M, int N, int K, int lda, int ldb, int ldc,
    int qscale_cols)
{
  __shared__ __align__(16) unsigned short sA[128 * 32];
  __shared__ __align__(16) unsigned short sB[128 * 32];
  const int tid = threadIdx.x;
  const int wave = tid >> 6, lane = tid & 63, l15 = lane & 15, quad = lane >> 4;
  const int wr = wave >> 1, wc = wave & 1;
  const int m0 = blockIdx.x * 128, n0 = blockIdx.y * 128;

  const floatx4 z4 = {0.f, 0.f, 0.f, 0.f};
  floatx4 acc[4][4];
  for (int i = 0; i < 4; ++i) for (int j = 0; j < 4; ++j) acc[i][j] = z4;

  const int NK = K >> 5;
  auto stage = [&](int kt) {
    const int k0 = kt << 5;
    for (int j = 0; j < 2; ++j) {
      const int ci = j * 256 + wave * 64 + lane;
      gld_lds16(A + (size_t)(m0 + (ci >> 2)) * lda + k0 + (ci & 3) * 8,
                &sA[(j * 256 + wave * 64) * 8]);
      gld_lds16(Bt + (size_t)(n0 + (ci >> 2)) * ldb + k0 + (ci & 3) * 8,
                &sB[(j * 256 + wave * 64) * 8]);
    }
  };

  stage(0);
  for (int kt = 0; kt < NK; ++kt) {
    __syncthreads();
    short8 af[4], bf[4];
    for (int mt = 0; mt < 4; ++mt)
      af[mt] = *(const short8*)&sA[(wr * 64 + mt * 16 + l15) * 32 + quad * 8];
    for (int nt = 0; nt < 4; ++nt)
      bf[nt] = *(const short8*)&sB[(wc * 64 + nt * 16 + l15) * 32 + quad * 8];
    for (int mt = 0; mt < 4; ++mt)
      for (int nt = 0; nt < 4; ++nt)
        acc[mt][nt] = MFMA_BF16(af[mt], bf[nt], acc[mt][nt]);
    __syncthreads();
    if (kt + 1 < NK) stage(kt + 1);
  }
  for (int mt = 0; mt < 4; ++mt)
    for (int nt = 0; nt < 4; ++nt)
      for (int r = 0; r < 4; ++r) {
        const int row = m0 + wr * 64 + mt * 16 + quad * 4 + r;
        const int col = n0 + wc * 64 + nt * 16 + l15;
        float v = acc[mt][nt][r];
        if (col < qscale_cols) v *= 0.04508422f;
        C[(size_t)row * ldc + col] = f2bf(v);
      }
}

// ---------------------------------------------------------------------------
// Fused 5x weight transpose (+dtype convert)
// ---------------------------------------------------------------------------
__global__ __launch_bounds__(256) void w_transpose5(
    const void* __restrict__ W0, const void* __restrict__ W1,
    const void* __restrict__ W2, const void* __restrict__ W3,
    const void* __restrict__ W4, unsigned short* __restrict__ WT,
    const int* __restrict__ flag)
{
  __shared__ __align__(16) unsigned short tile[64 * 72];
  const void* srcs[5] = {W0, W1, W2, W3, W4};
  const void* W = srcs[blockIdx.z];
  unsigned short* dst0 = WT + (size_t)blockIdx.z * 1024 * 1024;
  const int rb = blockIdx.x * 64, cb = blockIdx.y * 64;
  const int tid = threadIdx.x;
  const int r = tid >> 2, c = tid & 3;
  unsigned short tmp[16];
  if (*flag) {
    const unsigned short* src = (const unsigned short*)W + (size_t)(rb + r) * 1024 + cb + c * 16;
    *(uint4*)&tmp[0] = *(const uint4*)src;
    *(uint4*)&tmp[8] = *(const uint4*)(src + 8);
  } else {
    const float* src = (const float*)W + (size_t)(rb + r) * 1024 + cb + c * 16;
    for (int j = 0; j < 16; j += 4) {
      const float4 f = *(const float4*)(src + j);
      tmp[j + 0] = f2bf(f.x); tmp[j + 1] = f2bf(f.y);
      tmp[j + 2] = f2bf(f.z); tmp[j + 3] = f2bf(f.w);
    }
  }
  *(uint4*)&tile[r * 72 + c * 16] = *(uint4*)&tmp[0];
  *(uint4*)&tile[r * 72 + c * 16 + 8] = *(uint4*)&tmp[8];
  __syncthreads();
  const int oc = tid >> 2;
  unsigned short out[16];
  for (int j = 0; j < 16; ++j) out[j] = tile[(c * 16 + j) * 72 + oc];
  unsigned short* dst = dst0 + (size_t)(cb + oc) * 1024 + rb + c * 16;
  *(uint4*)dst = *(uint4*)&out[0];
  *(uint4*)(dst + 8) = *(uint4*)&out[8];
}

// ---------------------------------------------------------------------------
// V-transpose + r_k scaling (rsum computed inline from 4 partials):
// Vt[bh][d][s] = V[b,s,h*64+d] / sum_qs spart[(bh*2048+s)*4 + qs]
// ---------------------------------------------------------------------------
__global__ __launch_bounds__(256) void v_transpose(const unsigned short* __restrict__ QKV,
                                                   const float* __restrict__ spart,
                                                   unsigned short* __restrict__ Vt)
{
  __shared__ __align__(16) unsigned short tile[64 * 72];
  const int bh = blockIdx.x, st = blockIdx.y;
  const int b = bh >> 4, h = bh & 15;
  const int tid = threadIdx.x;
  const int r = tid >> 2, c = tid & 3;
  const unsigned short* src =
      QKV + (size_t)(b * 2048 + st * 64 + r) * 3072 + 2048 + h * 64 + c * 16;
  *(uint4*)&tile[r * 72 + c * 16] = *(const uint4*)src;
  *(uint4*)&tile[r * 72 + c * 16 + 8] = *(const uint4*)(src + 8);
  __syncthreads();
  const int d = tid >> 2;
  unsigned short out[16];
  for (int j = 0; j < 16; ++j) {
    const int s = st * 64 + c * 16 + j;
    const float4 sp = *(const float4*)&spart[(size_t)(bh * 2048 + s) * 4];
    const float rs = 1.0f / (sp.x + sp.y + sp.z + sp.w);
    out[j] = f2bf(bf2f(tile[(c * 16 + j) * 72 + d]) * rs);
  }
  unsigned short* dst = Vt + (size_t)bh * 64 * 2048 + (size_t)d * 2048 + st * 64 + c * 16;
  *(uint4*)dst = *(uint4*)&out[0];
  *(uint4*)(dst + 8) = *(uint4*)&out[8];
}

// ---------------------------------------------------------------------------
// Attention stats v3: spart[(bh*2048+k)*4 + qs] = sum_{q in 512-quarter}
// exp2(<K,Q'>).  128-q tiles (16 frags, 16 KB) double-buffered: compute per
// barrier ~780 cyc covers L3 staging latency; VGPR capped at 128 via
// __launch_bounds__(256,4); staging ptrs advance by constant stride.
// grid (16 kb, 4 qs, 32 bh), 4 waves x 32 k-rows.
// ---------------------------------------------------------------------------
__global__ __launch_bounds__(256, 4) void attn_stats(const unsigned short* __restrict__ QKV,
                                                     float* __restrict__ spart)
{
  __shared__ __align__(16) unsigned short sQ[2][16 * 512];  // 2 x 16 KB
  const int kb = blockIdx.x, qs = blockIdx.y, bh = blockIdx.z;
  const int b = bh >> 4, h = bh & 15;
  const int tid = threadIdx.x;
  const int wave = tid >> 6, lane = tid & 63, l15 = lane & 15, quad = lane >> 4;
  const int kbase = kb * 128 + wave * 32;
  const size_t row0 = (size_t)b * 2048;
  const int qoff = h * 64, koff = 1024 + h * 64;
  const int qbase = qs * 512;

  // A-operand: this wave's 32 K rows, in regs for the whole kernel
  short8 kf[2][2];
  for (int rt = 0; rt < 2; ++rt)
    for (int ks = 0; ks < 2; ++ks)
      kf[rt][ks] = *(const short8*)&QKV[(row0 + kbase + rt * 16 + l15) * 3072 +
                                        koff + ks * 32 + quad * 8];

  float l[2][4];
  for (int rt = 0; rt < 2; ++rt)
    for (int r = 0; r < 4; ++r) l[rt][r] = 0.f;

  // staging: 16 B-fragments per 128-q tile; wave stages frags wave*4..wave*4+3
  // frag f: nt = f>>1 (16-q subgroup), ks = f&1 (dh half)
  const unsigned short* gbase[4];
  for (int j = 0; j < 4; ++j) {
    const int f = wave * 4 + j;
    const int nt = f >> 1, ks = f & 1;
    gbase[j] = QKV + (row0 + qbase + nt * 16 + l15) * 3072 + qoff + ks * 32 + quad * 8;
  }
  auto stageQ = [&](int t) {
    const size_t adv = (size_t)t * (128 * 3072);   // 128 q-rows per tile
    for (int j = 0; j < 4; ++j)
      gld_lds16(gbase[j] + adv, &sQ[t & 1][(wave * 4 + j) * 512]);
  };

  const floatx4 z4 = {0.f, 0.f, 0.f, 0.f};
  stageQ(0);
  for (int t = 0; t < 4; ++t) {
    __syncthreads();                 // staging of t landed; t-1 reads done
    if (t + 1 < 4) stageQ(t + 1);
    const unsigned short* sQt = sQ[t & 1];
    for (int nt = 0; nt < 8; ++nt) {
      const short8 bq0 = *(const short8*)&sQt[(nt * 2 + 0) * 512 + lane * 8];
      const short8 bq1 = *(const short8*)&sQt[(nt * 2 + 1) * 512 + lane * 8];
      for (int rt = 0; rt < 2; ++rt) {
        floatx4 acc = z4;
        acc = MFMA_BF16(kf[rt][0], bq0, acc);
        acc = MFMA_BF16(kf[rt][1], bq1, acc);
        for (int r = 0; r < 4; ++r)
          l[rt][r] += EXP2F(acc[r]);
      }
    }
  }
  // sum across the 16 q-columns held by lanes sharing quad
  for (int rt = 0; rt < 2; ++rt)
    for (int r = 0; r < 4; ++r) {
      float ll = l[rt][r];
      ll += __shfl_xor(ll, 1, 64);
      ll += __shfl_xor(ll, 2, 64);
      ll += __shfl_xor(ll, 4, 64);
      ll += __shfl_xor(ll, 8, 64);
      if (l15 == 0) {
        const int krow = kbase + rt * 16 + quad * 4 + r;
        spart[(size_t)(bh * 2048 + krow) * 4 + qs] = ll;
      }
    }
}

// ---------------------------------------------------------------------------
// attn_pv2: Outp[kh][q,d] = sum_{k in half} exp2(<Q'_q,K_k>) * V'[k,d]
// S computed as D[k][q] (A=K, B=Q): its C-regs (k=quad*4+r, q=l15) are
// EXACTLY the B-operand layout of mfma_f32_16x16x16_bf16 -> P stays in regs.
// PV: A = V'-frag (m=d), accumulate Out^T[d][q]; one LDS transpose at end.
// grid (32 bh, 16 qb of 128, 2 k-halves); 4 waves x 32 q; k-tiles 64 dbuf.
// ---------------------------------------------------------------------------
__global__ __launch_bounds__(256) void attn_pv2(const unsigned short* __restrict__ QKV,
                                                const unsigned short* __restrict__ Vt,
                                                unsigned short* __restrict__ z1p0,
                                                unsigned short* __restrict__ z1p1)
{
  __shared__ __align__(16) unsigned char smem[32768];
  unsigned short* sK = (unsigned short*)smem;            // [2][64*64]
  unsigned short* sV = (unsigned short*)(smem + 16384);  // [2][64*64]
  unsigned short* sT = (unsigned short*)smem;            // [128][72] (epilogue)

  const int bh = blockIdx.x, qb = blockIdx.y, kh = blockIdx.z;
  const int b = bh >> 4, h = bh & 15;
  const int tid = threadIdx.x;
  const int wave = tid >> 6, lane = tid & 63, l15 = lane & 15, quad = lane >> 4;
  const size_t row0 = (size_t)b * 2048;
  const int qoff = h * 64, koff = 1024 + h * 64;
  const int q0 = qb * 128;
  const int srow = lane >> 3, schk = (lane & 7) ^ ((lane >> 3) & 7);

  // Q B-frags (B[dh][q], lane l15 = q), held in regs for the whole kernel
  short8 qf[2][2];  // [qg][ks]
  for (int qg = 0; qg < 2; ++qg)
    for (int ks = 0; ks < 2; ++ks)
      qf[qg][ks] = *(const short8*)&QKV[(row0 + q0 + wave * 32 + qg * 16 + l15) * 3072 +
                                        qoff + ks * 32 + quad * 8];

  const floatx4 z4 = {0.f, 0.f, 0.f, 0.f};
  floatx4 acc[4][2];  // [dg][qg] : Out^T[d][q]
  for (int i = 0; i < 4; ++i) for (int j = 0; j < 2; ++j) acc[i][j] = z4;

  const unsigned short* VtB = Vt + (size_t)bh * 64 * 2048;

  auto stage = [&](int kt) {
    const int kb = kh * 1024 + kt * 64;
    const int bo = (kt & 1) * 4096;
    for (int j = 0; j < 2; ++j) {
      const int jj = wave * 2 + j;  // 8-row group
      gld_lds16(QKV + (row0 + kb + jj * 8 + srow) * 3072 + koff + schk * 8,
                &sK[bo + jj * 512]);
      gld_lds16(VtB + (size_t)(jj * 8 + srow) * 2048 + kb + schk * 8,
                &sV[bo + jj * 512]);
    }
  };

  stage(0);
  for (int kt = 0; kt < 16; ++kt) {
    __syncthreads();
    if (kt + 1 < 16) stage(kt + 1);
    const unsigned short* sKt = &sK[(kt & 1) * 4096];
    const unsigned short* sVt = &sV[(kt & 1) * 4096];
    for (int kg = 0; kg < 4; ++kg) {     // 16-k groups in the 64-k tile
      // --- S tile D[k][q] for this kg: A = K rows, B = Q ---
      floatx4 s0 = z4, s1 = z4;
      for (int ks = 0; ks < 2; ++ks) {
        const short8 kfr = *(const short8*)
            &sKt[(kg * 16 + l15) * 64 + (((ks * 4 + quad) ^ (l15 & 7)) * 8)];
        s0 = MFMA_BF16(kfr, qf[0][ks], s0);
        s1 = MFMA_BF16(kfr, qf[1][ks], s1);
      }
      // --- P frags in regs: lane holds P[k=quad*4+r][q=l15] = B-op of K16 ---
      union PU { struct { __hip_bfloat162 lo, hi; } p; short4v v; };
      PU p0, p1;
      p0.p.lo = __float22bfloat162_rn(float2{EXP2F(s0[0]), EXP2F(s0[1])});
      p0.p.hi = __float22bfloat162_rn(float2{EXP2F(s0[2]), EXP2F(s0[3])});
      p1.p.lo = __float22bfloat162_rn(float2{EXP2F(s1[0]), EXP2F(s1[1])});
      p1.p.hi = __float22bfloat162_rn(float2{EXP2F(s1[2]), EXP2F(s1[3])});
      // --- Out^T += V'^T-frag @ P : A[m=d][k=quad*4+j] from sV b64 reads ---
      const int slot = (2 * kg + (quad >> 1)) ^ (l15 & 7);
      const int sub = (quad & 1) * 8;
      for (int dg = 0; dg < 4; ++dg) {
        const short4v vfr = *(const short4v*)
            ((const char*)&sVt[(dg * 16 + l15) * 64] + slot * 16 + sub);
        acc[dg][0] = MFMA16(vfr, p0.v, acc[dg][0]);
        acc[dg][1] = MFMA16(vfr, p1.v, acc[dg][1]);
      }
    }
  }
  // epilogue: transpose Out^T[d][q] -> [q][d] via LDS, store coalesced
  __syncthreads();
  for (int dg = 0; dg < 4; ++dg)
    for (int qg = 0; qg < 2; ++qg) {
      ushort4 pk = {f2bf(acc[dg][qg][0]), f2bf(acc[dg][qg][1]),
                    f2bf(acc[dg][qg][2]), f2bf(acc[dg][qg][3])};
      *(ushort4*)&sT[(wave * 32 + qg * 16 + l15) * 72 + dg * 16 + quad * 4] = pk;
    }
  __syncthreads();
  unsigned short* z1p = kh ? z1p1 : z1p0;
  const int q = tid >> 1, d0 = (tid & 1) * 32;
  unsigned short* dst = z1p + (row0 + q0 + q) * 1024 + qoff + d0;
  const unsigned short* srcT = &sT[q * 72 + d0];
  for (int j = 0; j < 4; ++j)
    *(uint4*)(dst + j * 8) = *(const uint4*)(srcT + j * 8);
}

// z1 = bf16(z1p0 + z1p1), 4096x1024 elements, 8 per thread
__global__ __launch_bounds__(256) void pv_combine(const unsigned short* __restrict__ z1p0,
                                                  const unsigned short* __restrict__ z1p1,
                                                  unsigned short* __restrict__ z1)
{
  const int i = blockIdx.x * 256 + threadIdx.x;
  const uint4 a = ((const uint4*)z1p0)[i];
  const uint4 b = ((const uint4*)z1p1)[i];
  const unsigned short* av = (const unsigned short*)&a;
  const unsigned short* bv = (const unsigned short*)&b;
  unsigned short o[8];
  for (int j = 0; j < 8; ++j) o[j] = f2bf(bf2f(av[j]) + bf2f(bv[j]));
  ((uint4*)z1)[i] = *(uint4*)o;
}

// ---------------------------------------------------------------------------
// Row-wise L2 normalize (1024 cols) + exact-erf GELU.  1 block/row.
// ---------------------------------------------------------------------------
__global__ __launch_bounds__(256) void l2norm_gelu(const unsigned short* __restrict__ in,
                                                   void* __restrict__ out, int do_gelu,
                                                   int fin, const int* __restrict__ flag)
{
  __shared__ float red[4];
  const int row = blockIdx.x, tid = threadIdx.x;
  const unsigned short* p = in + (size_t)row * 1024 + tid * 4;
  const ushort4 u = *(const ushort4*)p;
  float x[4] = {bf2f(u.x), bf2f(u.y), bf2f(u.z), bf2f(u.w)};
  float ss = x[0] * x[0] + x[1] * x[1] + x[2] * x[2] + x[3] * x[3];
  for (int off = 32; off > 0; off >>= 1) ss += __shfl_down(ss, off, 64);
  if ((tid & 63) == 0) red[tid >> 6] = ss;
  __syncthreads();
  const float tot = red[0] + red[1] + red[2] + red[3];
  const float sc = 1.0f / fmaxf(sqrtf(tot), 1e-12f);
  float y[4];
  for (int j = 0; j < 4; ++j) {
    y[j] = x[j] * sc;
    if (do_gelu) y[j] = 0.5f * y[j] * (1.0f + erff(y[j] * 0.70710678118654752f));
  }
  if (fin && *flag == 0) {
    float4 o = {y[0], y[1], y[2], y[3]};
    ((float4*)out)[(size_t)row * 256 + tid] = o;
  } else {
    ushort4 o = {f2bf(y[0]), f2bf(y[1]), f2bf(y[2]), f2bf(y[3])};
    ((ushort4*)out)[(size_t)row * 256 + tid] = o;
  }
}

// ---------------------------------------------------------------------------
extern "C" void kernel_launch(void* const* d_in, const int* in_sizes, int n_in,
                              void* d_out, int out_size, void* d_ws, size_t ws_size,
                              hipStream_t stream)
{
  const void* x   = d_in[0];
  const void* Wq  = d_in[1];
  const void* Wk  = d_in[2];
  const void* Wv  = d_in[3];
  const void* Wo  = d_in[4];
  const void* Wff = d_in[5];

  char* ws = (char*)d_ws;
  size_t off = 0;
  auto alloc = [&](size_t bytes) -> void* {
    void* p = ws + off; off += (bytes + 255) & ~(size_t)255; return p;
  };
  int* flag             = (int*)alloc(256);
  unsigned short* xb    = (unsigned short*)alloc((size_t)4096 * 1024 * 2);  // 8 MB
  unsigned short* WT    = (unsigned short*)alloc((size_t)5 * 1024 * 1024 * 2); // 10 MB
  unsigned short* QKV   = (unsigned short*)alloc((size_t)4096 * 3072 * 2);  // 24 MB
  unsigned short* Vt    = (unsigned short*)alloc((size_t)32 * 64 * 2048 * 2); // 8 MB
  float* spart          = (float*)alloc((size_t)65536 * 4 * 4);             // 1 MB
  unsigned short* z1    = (unsigned short*)alloc((size_t)4096 * 1024 * 2);  // 8 MB
  unsigned short* z1p1  = (unsigned short*)alloc((size_t)4096 * 1024 * 2);  // 8 MB
  unsigned short* WTqkv = WT;
  unsigned short* WoT   = WT + (size_t)3 * 1024 * 1024;
  unsigned short* WffT  = WT + (size_t)4 * 1024 * 1024;
  // aliases onto dead regions:
  unsigned short* z1p0 = xb;    // xb dead after QKV gemm
  unsigned short* z2   = Vt;    // Vt dead after attn_pv2
  unsigned short* z3   = QKV;   // QKV dead after attn_pv2

  detect_dtype<<<1, 256, 0, stream>>>((const unsigned int*)x, flag);
  cvt_x<<<2048, 256, 0, stream>>>(x, xb, flag);
  w_transpose5<<<dim3(16, 16, 5), 256, 0, stream>>>(Wq, Wk, Wv, Wo, Wff, WT, flag);

  gemm_bt_128x128<<<dim3(32, 24), 256, 0, stream>>>(xb, WTqkv, QKV,
                                                    4096, 3072, 1024, 1024, 1024, 3072, 1024);
  attn_stats<<<dim3(16, 4, 32), 256, 0, stream>>>(QKV, spart);
  v_transpose<<<dim3(32, 32), 256, 0, stream>>>(QKV, spart, Vt);
  attn_pv2<<<dim3(32, 16, 2), 256, 0, stream>>>(QKV, Vt, z1p0, z1p1);
  pv_combine<<<2048, 256, 0, stream>>>(z1p0, z1p1, z1);

  gemm_bt_128x64<<<dim3(32, 16), 256, 0, stream>>>(z1, WoT, z2,
                                                   4096, 1024, 1024, 1024, 1024, 1024, 0);
  // first l2norm dropped: l2norm(l2norm(z2)@Wff) == l2norm(z2@Wff) exactly
  gemm_bt_128x64<<<dim3(32, 16), 256, 0, stream>>>(z2, WffT, z3,
                                                   4096, 1024, 1024, 1024, 1024, 1024, 0);
  l2norm_gelu<<<4096, 256, 0, stream>>>(z3, d_out, 1, 1, flag);
}

// Round 10
// 302.492 us; speedup vs baseline: 1.2226x; 1.2226x over previous
//
#include <hip/hip_runtime.h>
#include <hip/hip_bf16.h>
#include <stdint.h>

// ---------------------------------------------------------------------------
// DecoderOnlyTransformer: x@Wq/Wk/Wv -> transposed-softmax attention -> @Wo
//   -> (l2norm dropped: exact cancellation) -> @Wff -> l2norm -> gelu(exact).
// B=2 S=2048 D=L=1024 H=16 dh=64.  Inputs fp32 (auto-detect fallback).
// Softmax over QUERY axis; |scores|<1 so max-subtraction dropped (exact).
// Q pre-scaled by 0.03125*log2(e); V rows pre-scaled by r_k.
// attn_pv2: S computed in D[k][q] layout whose C-regs ARE the B-operand of
// mfma 16x16x16 -> P never touches LDS.
// LESSON (round 7): never gate LAUNCH-site code on __has_builtin.
// LESSON (round 9): __launch_bounds__ VGPR caps below natural usage cause
// scratch spill -> 500+ MB of HBM round-trip; attn_stats reverted to the
// round-8 shape (64-q tiles, no cap).
// ---------------------------------------------------------------------------

typedef __attribute__((ext_vector_type(8))) short short8;   // 8 x bf16
typedef __attribute__((ext_vector_type(4))) short short4v;  // 4 x bf16
typedef __attribute__((ext_vector_type(4))) float floatx4;

#define MFMA_BF16(a, b, c) __builtin_amdgcn_mfma_f32_16x16x32_bf16((a), (b), (c), 0, 0, 0)
#define MFMA16(a, b, c) __builtin_amdgcn_mfma_f32_16x16x16bf16_1k((a), (b), (c), 0, 0, 0)

#if defined(__HIP_DEVICE_COMPILE__)
#define EXP2F(x) __builtin_amdgcn_exp2f(x)
#else
#define EXP2F(x) exp2f(x)
#endif

__device__ __forceinline__ float bf2f(unsigned short u) {
  union { unsigned int i; float f; } v; v.i = ((unsigned int)u) << 16; return v.f;
}
__device__ __forceinline__ unsigned short f2bf(float f) {
  __hip_bfloat16 h = __float2bfloat16(f);
  return *reinterpret_cast<unsigned short*>(&h);
}
__device__ __forceinline__ void gld_lds16(const void* g, void* l) {
  __builtin_amdgcn_global_load_lds((__attribute__((address_space(1))) void*)g,
                                   (__attribute__((address_space(3))) void*)l,
                                   16, 0, 0);
}

// ---------------------------------------------------------------------------
__global__ __launch_bounds__(256) void detect_dtype(const unsigned int* __restrict__ x,
                                                    int* __restrict__ flag)
{
  __shared__ int red[4];
  int ok = 0;
  for (int i = 0; i < 16; ++i) {
    const unsigned int w = x[threadIdx.x * 16 + i];
    const unsigned int e = (w >> 7) & 0xFF;
    ok += (e == 0 || (e >= 96 && e <= 144)) ? 1 : 0;
  }
  for (int off = 32; off > 0; off >>= 1) ok += __shfl_down(ok, off, 64);
  if ((threadIdx.x & 63) == 0) red[threadIdx.x >> 6] = ok;
  __syncthreads();
  if (threadIdx.x == 0)
    *flag = ((red[0] + red[1] + red[2] + red[3]) > 2048) ? 1 : 0;
}

__global__ __launch_bounds__(256) void cvt_x(const void* __restrict__ src,
                                             unsigned short* __restrict__ dst,
                                             const int* __restrict__ flag)
{
  const int i = blockIdx.x * 256 + threadIdx.x;
  if (*flag) {
    ((uint4*)dst)[i] = ((const uint4*)src)[i];
  } else {
    const float4 a = ((const float4*)src)[2 * i];
    const float4 b = ((const float4*)src)[2 * i + 1];
    unsigned short o[8] = {f2bf(a.x), f2bf(a.y), f2bf(a.z), f2bf(a.w),
                           f2bf(b.x), f2bf(b.y), f2bf(b.z), f2bf(b.w)};
    ((uint4*)dst)[i] = *(uint4*)o;
  }
}

// ---------------------------------------------------------------------------
// C[M,N] = A[M,K] @ Bt[N,K]^T, tile 128x128 (m97 shape), BK=32, 2x2 waves.
// Each b128 LDS read feeds 4 MFMAs.  Used for all dense GEMMs.
// ---------------------------------------------------------------------------
__global__ __launch_bounds__(256) void gemm_bt_128x128(
    const unsigned short* __restrict__ A, const unsigned short* __restrict__ Bt,
    unsigned short* __restrict__ C, int M, int N, int K, int lda, int ldb, int ldc,
    int qscale_cols)
{
  __shared__ __align__(16) unsigned short sA[128 * 32];
  __shared__ __align__(16) unsigned short sB[128 * 32];
  const int tid = threadIdx.x;
  const int wave = tid >> 6, lane = tid & 63, l15 = lane & 15, quad = lane >> 4;
  const int wr = wave >> 1, wc = wave & 1;
  const int m0 = blockIdx.x * 128, n0 = blockIdx.y * 128;

  const floatx4 z4 = {0.f, 0.f, 0.f, 0.f};
  floatx4 acc[4][4];
  for (int i = 0; i < 4; ++i) for (int j = 0; j < 4; ++j) acc[i][j] = z4;

  const int NK = K >> 5;
  auto stage = [&](int kt) {
    const int k0 = kt << 5;
    for (int j = 0; j < 2; ++j) {
      const int ci = j * 256 + wave * 64 + lane;
      gld_lds16(A + (size_t)(m0 + (ci >> 2)) * lda + k0 + (ci & 3) * 8,
                &sA[(j * 256 + wave * 64) * 8]);
      gld_lds16(Bt + (size_t)(n0 + (ci >> 2)) * ldb + k0 + (ci & 3) * 8,
                &sB[(j * 256 + wave * 64) * 8]);
    }
  };

  stage(0);
  for (int kt = 0; kt < NK; ++kt) {
    __syncthreads();
    short8 af[4], bf[4];
    for (int mt = 0; mt < 4; ++mt)
      af[mt] = *(const short8*)&sA[(wr * 64 + mt * 16 + l15) * 32 + quad * 8];
    for (int nt = 0; nt < 4; ++nt)
      bf[nt] = *(const short8*)&sB[(wc * 64 + nt * 16 + l15) * 32 + quad * 8];
    for (int mt = 0; mt < 4; ++mt)
      for (int nt = 0; nt < 4; ++nt)
        acc[mt][nt] = MFMA_BF16(af[mt], bf[nt], acc[mt][nt]);
    __syncthreads();
    if (kt + 1 < NK) stage(kt + 1);
  }
  for (int mt = 0; mt < 4; ++mt)
    for (int nt = 0; nt < 4; ++nt)
      for (int r = 0; r < 4; ++r) {
        const int row = m0 + wr * 64 + mt * 16 + quad * 4 + r;
        const int col = n0 + wc * 64 + nt * 16 + l15;
        float v = acc[mt][nt][r];
        if (col < qscale_cols) v *= 0.04508422f;
        C[(size_t)row * ldc + col] = f2bf(v);
      }
}

// ---------------------------------------------------------------------------
// Fused 5x weight transpose (+dtype convert)
// ---------------------------------------------------------------------------
__global__ __launch_bounds__(256) void w_transpose5(
    const void* __restrict__ W0, const void* __restrict__ W1,
    const void* __restrict__ W2, const void* __restrict__ W3,
    const void* __restrict__ W4, unsigned short* __restrict__ WT,
    const int* __restrict__ flag)
{
  __shared__ __align__(16) unsigned short tile[64 * 72];
  const void* srcs[5] = {W0, W1, W2, W3, W4};
  const void* W = srcs[blockIdx.z];
  unsigned short* dst0 = WT + (size_t)blockIdx.z * 1024 * 1024;
  const int rb = blockIdx.x * 64, cb = blockIdx.y * 64;
  const int tid = threadIdx.x;
  const int r = tid >> 2, c = tid & 3;
  unsigned short tmp[16];
  if (*flag) {
    const unsigned short* src = (const unsigned short*)W + (size_t)(rb + r) * 1024 + cb + c * 16;
    *(uint4*)&tmp[0] = *(const uint4*)src;
    *(uint4*)&tmp[8] = *(const uint4*)(src + 8);
  } else {
    const float* src = (const float*)W + (size_t)(rb + r) * 1024 + cb + c * 16;
    for (int j = 0; j < 16; j += 4) {
      const float4 f = *(const float4*)(src + j);
      tmp[j + 0] = f2bf(f.x); tmp[j + 1] = f2bf(f.y);
      tmp[j + 2] = f2bf(f.z); tmp[j + 3] = f2bf(f.w);
    }
  }
  *(uint4*)&tile[r * 72 + c * 16] = *(uint4*)&tmp[0];
  *(uint4*)&tile[r * 72 + c * 16 + 8] = *(uint4*)&tmp[8];
  __syncthreads();
  const int oc = tid >> 2;
  unsigned short out[16];
  for (int j = 0; j < 16; ++j) out[j] = tile[(c * 16 + j) * 72 + oc];
  unsigned short* dst = dst0 + (size_t)(cb + oc) * 1024 + rb + c * 16;
  *(uint4*)dst = *(uint4*)&out[0];
  *(uint4*)(dst + 8) = *(uint4*)&out[8];
}

// ---------------------------------------------------------------------------
// V-transpose + r_k scaling (rsum computed inline from 4 partials):
// Vt[bh][d][s] = V[b,s,h*64+d] / sum_qs spart[(bh*2048+s)*4 + qs]
// ---------------------------------------------------------------------------
__global__ __launch_bounds__(256) void v_transpose(const unsigned short* __restrict__ QKV,
                                                   const float* __restrict__ spart,
                                                   unsigned short* __restrict__ Vt)
{
  __shared__ __align__(16) unsigned short tile[64 * 72];
  const int bh = blockIdx.x, st = blockIdx.y;
  const int b = bh >> 4, h = bh & 15;
  const int tid = threadIdx.x;
  const int r = tid >> 2, c = tid & 3;
  const unsigned short* src =
      QKV + (size_t)(b * 2048 + st * 64 + r) * 3072 + 2048 + h * 64 + c * 16;
  *(uint4*)&tile[r * 72 + c * 16] = *(const uint4*)src;
  *(uint4*)&tile[r * 72 + c * 16 + 8] = *(const uint4*)(src + 8);
  __syncthreads();
  const int d = tid >> 2;
  unsigned short out[16];
  for (int j = 0; j < 16; ++j) {
    const int s = st * 64 + c * 16 + j;
    const float4 sp = *(const float4*)&spart[(size_t)(bh * 2048 + s) * 4];
    const float rs = 1.0f / (sp.x + sp.y + sp.z + sp.w);
    out[j] = f2bf(bf2f(tile[(c * 16 + j) * 72 + d]) * rs);
  }
  unsigned short* dst = Vt + (size_t)bh * 64 * 2048 + (size_t)d * 2048 + st * 64 + c * 16;
  *(uint4*)dst = *(uint4*)&out[0];
  *(uint4*)(dst + 8) = *(uint4*)&out[8];
}

// ---------------------------------------------------------------------------
// Attention stats (round-8 known-good): spart[(bh*2048+k)*4 + qs] =
// sum_{q in 512-quarter} exp2(<K,Q'>).  64-q tiles staged fragment-major via
// global_load_lds, double-buffered.  grid (32 bh, 16 kb, 4 qs).
// ---------------------------------------------------------------------------
__global__ __launch_bounds__(256) void attn_stats(const unsigned short* __restrict__ QKV,
                                                  float* __restrict__ spart)
{
  __shared__ __align__(16) unsigned short sQ[2][8 * 512];
  const int bh = blockIdx.x, kb = blockIdx.y, qs = blockIdx.z;
  const int b = bh >> 4, h = bh & 15;
  const int tid = threadIdx.x;
  const int wave = tid >> 6, lane = tid & 63, l15 = lane & 15, quad = lane >> 4;
  const int kbase = kb * 128 + wave * 32;
  const size_t row0 = (size_t)b * 2048;
  const int qoff = h * 64, koff = 1024 + h * 64;
  const int qbase = qs * 512;

  short8 kf[2][2];
  for (int rt = 0; rt < 2; ++rt)
    for (int ks = 0; ks < 2; ++ks)
      kf[rt][ks] = *(const short8*)&QKV[(row0 + kbase + rt * 16 + l15) * 3072 +
                                        koff + ks * 32 + quad * 8];

  float l[2][4];
  for (int rt = 0; rt < 2; ++rt)
    for (int r = 0; r < 4; ++r) l[rt][r] = 0.f;

  auto stageQ = [&](int t) {
    const int qt0 = qbase + t * 64;
    for (int j = 0; j < 2; ++j) {
      const int f = wave * 2 + j;
      const int nt = f >> 1, ks = f & 1;
      gld_lds16(QKV + (row0 + qt0 + nt * 16 + l15) * 3072 + qoff + ks * 32 + quad * 8,
                &sQ[t & 1][f * 512]);
    }
  };

  const floatx4 z4 = {0.f, 0.f, 0.f, 0.f};
  stageQ(0);
  for (int t = 0; t < 8; ++t) {
    __syncthreads();
    if (t + 1 < 8) stageQ(t + 1);
    const unsigned short* sQt = sQ[t & 1];
    for (int nt = 0; nt < 4; ++nt) {
      const short8 bq0 = *(const short8*)&sQt[(nt * 2 + 0) * 512 + lane * 8];
      const short8 bq1 = *(const short8*)&sQt[(nt * 2 + 1) * 512 + lane * 8];
      for (int rt = 0; rt < 2; ++rt) {
        floatx4 acc = z4;
        acc = MFMA_BF16(kf[rt][0], bq0, acc);
        acc = MFMA_BF16(kf[rt][1], bq1, acc);
        for (int r = 0; r < 4; ++r)
          l[rt][r] += EXP2F(acc[r]);
      }
    }
  }
  for (int rt = 0; rt < 2; ++rt)
    for (int r = 0; r < 4; ++r) {
      float ll = l[rt][r];
      ll += __shfl_xor(ll, 1, 64);
      ll += __shfl_xor(ll, 2, 64);
      ll += __shfl_xor(ll, 4, 64);
      ll += __shfl_xor(ll, 8, 64);
      if (l15 == 0) {
        const int krow = kbase + rt * 16 + quad * 4 + r;
        spart[(size_t)(bh * 2048 + krow) * 4 + qs] = ll;
      }
    }
}

// ---------------------------------------------------------------------------
// attn_pv2: Outp[kh][q,d] = sum_{k in half} exp2(<Q'_q,K_k>) * V'[k,d]
// S computed as D[k][q] (A=K, B=Q): its C-regs (k=quad*4+r, q=l15) are
// EXACTLY the B-operand layout of mfma_f32_16x16x16_bf16 -> P stays in regs.
// PV: A = V'-frag (m=d), accumulate Out^T[d][q]; one LDS transpose at end.
// grid (32 bh, 16 qb of 128, 2 k-halves); 4 waves x 32 q; k-tiles 64 dbuf.
// ---------------------------------------------------------------------------
__global__ __launch_bounds__(256) void attn_pv2(const unsigned short* __restrict__ QKV,
                                                const unsigned short* __restrict__ Vt,
                                                unsigned short* __restrict__ z1p0,
                                                unsigned short* __restrict__ z1p1)
{
  __shared__ __align__(16) unsigned char smem[32768];
  unsigned short* sK = (unsigned short*)smem;            // [2][64*64]
  unsigned short* sV = (unsigned short*)(smem + 16384);  // [2][64*64]
  unsigned short* sT = (unsigned short*)smem;            // [128][72] (epilogue)

  const int bh = blockIdx.x, qb = blockIdx.y, kh = blockIdx.z;
  const int b = bh >> 4, h = bh & 15;
  const int tid = threadIdx.x;
  const int wave = tid >> 6, lane = tid & 63, l15 = lane & 15, quad = lane >> 4;
  const size_t row0 = (size_t)b * 2048;
  const int qoff = h * 64, koff = 1024 + h * 64;
  const int q0 = qb * 128;
  const int srow = lane >> 3, schk = (lane & 7) ^ ((lane >> 3) & 7);

  // Q B-frags (B[dh][q], lane l15 = q), held in regs for the whole kernel
  short8 qf[2][2];  // [qg][ks]
  for (int qg = 0; qg < 2; ++qg)
    for (int ks = 0; ks < 2; ++ks)
      qf[qg][ks] = *(const short8*)&QKV[(row0 + q0 + wave * 32 + qg * 16 + l15) * 3072 +
                                        qoff + ks * 32 + quad * 8];

  const floatx4 z4 = {0.f, 0.f, 0.f, 0.f};
  floatx4 acc[4][2];  // [dg][qg] : Out^T[d][q]
  for (int i = 0; i < 4; ++i) for (int j = 0; j < 2; ++j) acc[i][j] = z4;

  const unsigned short* VtB = Vt + (size_t)bh * 64 * 2048;

  auto stage = [&](int kt) {
    const int kb = kh * 1024 + kt * 64;
    const int bo = (kt & 1) * 4096;
    for (int j = 0; j < 2; ++j) {
      const int jj = wave * 2 + j;  // 8-row group
      gld_lds16(QKV + (row0 + kb + jj * 8 + srow) * 3072 + koff + schk * 8,
                &sK[bo + jj * 512]);
      gld_lds16(VtB + (size_t)(jj * 8 + srow) * 2048 + kb + schk * 8,
                &sV[bo + jj * 512]);
    }
  };

  stage(0);
  for (int kt = 0; kt < 16; ++kt) {
    __syncthreads();
    if (kt + 1 < 16) stage(kt + 1);
    const unsigned short* sKt = &sK[(kt & 1) * 4096];
    const unsigned short* sVt = &sV[(kt & 1) * 4096];
    for (int kg = 0; kg < 4; ++kg) {     // 16-k groups in the 64-k tile
      // --- S tile D[k][q] for this kg: A = K rows, B = Q ---
      floatx4 s0 = z4, s1 = z4;
      for (int ks = 0; ks < 2; ++ks) {
        const short8 kfr = *(const short8*)
            &sKt[(kg * 16 + l15) * 64 + (((ks * 4 + quad) ^ (l15 & 7)) * 8)];
        s0 = MFMA_BF16(kfr, qf[0][ks], s0);
        s1 = MFMA_BF16(kfr, qf[1][ks], s1);
      }
      // --- P frags in regs: lane holds P[k=quad*4+r][q=l15] = B-op of K16 ---
      union PU { struct { __hip_bfloat162 lo, hi; } p; short4v v; };
      PU p0, p1;
      p0.p.lo = __float22bfloat162_rn(float2{EXP2F(s0[0]), EXP2F(s0[1])});
      p0.p.hi = __float22bfloat162_rn(float2{EXP2F(s0[2]), EXP2F(s0[3])});
      p1.p.lo = __float22bfloat162_rn(float2{EXP2F(s1[0]), EXP2F(s1[1])});
      p1.p.hi = __float22bfloat162_rn(float2{EXP2F(s1[2]), EXP2F(s1[3])});
      // --- Out^T += V'^T-frag @ P : A[m=d][k=quad*4+j] from sV b64 reads ---
      const int slot = (2 * kg + (quad >> 1)) ^ (l15 & 7);
      const int sub = (quad & 1) * 8;
      for (int dg = 0; dg < 4; ++dg) {
        const short4v vfr = *(const short4v*)
            ((const char*)&sVt[(dg * 16 + l15) * 64] + slot * 16 + sub);
        acc[dg][0] = MFMA16(vfr, p0.v, acc[dg][0]);
        acc[dg][1] = MFMA16(vfr, p1.v, acc[dg][1]);
      }
    }
  }
  // epilogue: transpose Out^T[d][q] -> [q][d] via LDS, store coalesced
  __syncthreads();
  for (int dg = 0; dg < 4; ++dg)
    for (int qg = 0; qg < 2; ++qg) {
      ushort4 pk = {f2bf(acc[dg][qg][0]), f2bf(acc[dg][qg][1]),
                    f2bf(acc[dg][qg][2]), f2bf(acc[dg][qg][3])};
      *(ushort4*)&sT[(wave * 32 + qg * 16 + l15) * 72 + dg * 16 + quad * 4] = pk;
    }
  __syncthreads();
  unsigned short* z1p = kh ? z1p1 : z1p0;
  const int q = tid >> 1, d0 = (tid & 1) * 32;
  unsigned short* dst = z1p + (row0 + q0 + q) * 1024 + qoff + d0;
  const unsigned short* srcT = &sT[q * 72 + d0];
  for (int j = 0; j < 4; ++j)
    *(uint4*)(dst + j * 8) = *(const uint4*)(srcT + j * 8);
}

// z1 = bf16(z1p0 + z1p1), 4096x1024 elements, 8 per thread
__global__ __launch_bounds__(256) void pv_combine(const unsigned short* __restrict__ z1p0,
                                                  const unsigned short* __restrict__ z1p1,
                                                  unsigned short* __restrict__ z1)
{
  const int i = blockIdx.x * 256 + threadIdx.x;
  const uint4 a = ((const uint4*)z1p0)[i];
  const uint4 b = ((const uint4*)z1p1)[i];
  const unsigned short* av = (const unsigned short*)&a;
  const unsigned short* bv = (const unsigned short*)&b;
  unsigned short o[8];
  for (int j = 0; j < 8; ++j) o[j] = f2bf(bf2f(av[j]) + bf2f(bv[j]));
  ((uint4*)z1)[i] = *(uint4*)o;
}

// ---------------------------------------------------------------------------
// Row-wise L2 normalize (1024 cols) + exact-erf GELU.  1 block/row.
// ---------------------------------------------------------------------------
__global__ __launch_bounds__(256) void l2norm_gelu(const unsigned short* __restrict__ in,
                                                   void* __restrict__ out, int do_gelu,
                                                   int fin, const int* __restrict__ flag)
{
  __shared__ float red[4];
  const int row = blockIdx.x, tid = threadIdx.x;
  const unsigned short* p = in + (size_t)row * 1024 + tid * 4;
  const ushort4 u = *(const ushort4*)p;
  float x[4] = {bf2f(u.x), bf2f(u.y), bf2f(u.z), bf2f(u.w)};
  float ss = x[0] * x[0] + x[1] * x[1] + x[2] * x[2] + x[3] * x[3];
  for (int off = 32; off > 0; off >>= 1) ss += __shfl_down(ss, off, 64);
  if ((tid & 63) == 0) red[tid >> 6] = ss;
  __syncthreads();
  const float tot = red[0] + red[1] + red[2] + red[3];
  const float sc = 1.0f / fmaxf(sqrtf(tot), 1e-12f);
  float y[4];
  for (int j = 0; j < 4; ++j) {
    y[j] = x[j] * sc;
    if (do_gelu) y[j] = 0.5f * y[j] * (1.0f + erff(y[j] * 0.70710678118654752f));
  }
  if (fin && *flag == 0) {
    float4 o = {y[0], y[1], y[2], y[3]};
    ((float4*)out)[(size_t)row * 256 + tid] = o;
  } else {
    ushort4 o = {f2bf(y[0]), f2bf(y[1]), f2bf(y[2]), f2bf(y[3])};
    ((ushort4*)out)[(size_t)row * 256 + tid] = o;
  }
}

// ---------------------------------------------------------------------------
extern "C" void kernel_launch(void* const* d_in, const int* in_sizes, int n_in,
                              void* d_out, int out_size, void* d_ws, size_t ws_size,
                              hipStream_t stream)
{
  const void* x   = d_in[0];
  const void* Wq  = d_in[1];
  const void* Wk  = d_in[2];
  const void* Wv  = d_in[3];
  const void* Wo  = d_in[4];
  const void* Wff = d_in[5];

  char* ws = (char*)d_ws;
  size_t off = 0;
  auto alloc = [&](size_t bytes) -> void* {
    void* p = ws + off; off += (bytes + 255) & ~(size_t)255; return p;
  };
  int* flag             = (int*)alloc(256);
  unsigned short* xb    = (unsigned short*)alloc((size_t)4096 * 1024 * 2);  // 8 MB
  unsigned short* WT    = (unsigned short*)alloc((size_t)5 * 1024 * 1024 * 2); // 10 MB
  unsigned short* QKV   = (unsigned short*)alloc((size_t)4096 * 3072 * 2);  // 24 MB
  unsigned short* Vt    = (unsigned short*)alloc((size_t)32 * 64 * 2048 * 2); // 8 MB
  float* spart          = (float*)alloc((size_t)65536 * 4 * 4);             // 1 MB
  unsigned short* z1    = (unsigned short*)alloc((size_t)4096 * 1024 * 2);  // 8 MB
  unsigned short* z1p1  = (unsigned short*)alloc((size_t)4096 * 1024 * 2);  // 8 MB
  unsigned short* WTqkv = WT;
  unsigned short* WoT   = WT + (size_t)3 * 1024 * 1024;
  unsigned short* WffT  = WT + (size_t)4 * 1024 * 1024;
  // aliases onto dead regions:
  unsigned short* z1p0 = xb;    // xb dead after QKV gemm
  unsigned short* z2   = Vt;    // Vt dead after attn_pv2
  unsigned short* z3   = QKV;   // QKV dead after attn_pv2

  detect_dtype<<<1, 256, 0, stream>>>((const unsigned int*)x, flag);
  cvt_x<<<2048, 256, 0, stream>>>(x, xb, flag);
  w_transpose5<<<dim3(16, 16, 5), 256, 0, stream>>>(Wq, Wk, Wv, Wo, Wff, WT, flag);

  gemm_bt_128x128<<<dim3(32, 24), 256, 0, stream>>>(xb, WTqkv, QKV,
                                                    4096, 3072, 1024, 1024, 1024, 3072, 1024);
  attn_stats<<<dim3(32, 16, 4), 256, 0, stream>>>(QKV, spart);
  v_transpose<<<dim3(32, 32), 256, 0, stream>>>(QKV, spart, Vt);
  attn_pv2<<<dim3(32, 16, 2), 256, 0, stream>>>(QKV, Vt, z1p0, z1p1);
  pv_combine<<<2048, 256, 0, stream>>>(z1p0, z1p1, z1);

  gemm_bt_128x128<<<dim3(32, 8), 256, 0, stream>>>(z1, WoT, z2,
                                                   4096, 1024, 1024, 1024, 1024, 1024, 0);
  // first l2norm dropped: l2norm(l2norm(z2)@Wff) == l2norm(z2@Wff) exactly
  gemm_bt_128x128<<<dim3(32, 8), 256, 0, stream>>>(z2, WffT, z3,
                                                   4096, 1024, 1024, 1024, 1024, 1024, 0);
  l2norm_gelu<<<4096, 256, 0, stream>>>(z3, d_out, 1, 1, flag);
}